// Round 19
// baseline (321.612 us; speedup 1.0000x reference)
//
#include <hip/hip_runtime.h>

#define NN 50000
#define NHALF 25000
#define NE 800000
#define HIST_BLOCKS ((NE + 255) / 256)   // 3125
#define FILL_BLOCKS HIST_BLOCKS          // 3125
#define FC_BLOCKS 1024
#define HBSZ ((size_t)(NN + 1) * 64)     // u16 elems per H table (row NN = zeros)

typedef unsigned short u16;
typedef unsigned int u32;

__device__ inline float rlf(float v, int l) {
    return __int_as_float(__builtin_amdgcn_readlane(__float_as_int(v), l));
}
__device__ inline u16 f2bf(float f) {  // round-to-nearest-even
    u32 u = __float_as_uint(f);
    u32 r = (u + 0x7FFFu + ((u >> 16) & 1u)) >> 16;
    return (u16)r;
}
__device__ inline float lo16(u32 q) { return __uint_as_float(q << 16); }
__device__ inline float hi16(u32 q) { return __uint_as_float(q & 0xffff0000u); }

// ------- hist (edges, also records per-edge rank) + weight-fold dual-role ---
__global__ __launch_bounds__(256) void k_hist_foldw(
    const int* __restrict__ dst, int* __restrict__ cnt, u16* __restrict__ rank,
    const float* __restrict__ fc2W, const float* __restrict__ b2,
    const float* __restrict__ c1W, float* __restrict__ W2c,
    float* __restrict__ b2c) {
    if (blockIdx.x < HIST_BLOCKS) {
        int e = blockIdx.x * 256 + threadIdx.x;
        if (e < NE) {
            u16 r = (u16)atomicAdd(&cnt[dst[e]], 1);
            __builtin_nontemporal_store(r, &rank[e]);
        }
    } else {
        int j = (blockIdx.x - HIST_BLOCKS) * 4 + (threadIdx.x >> 6);
        int c = threadIdx.x & 63;
        if (j < 32) {
            float s = 0.f;
            for (int k = 0; k < 64; ++k) s = fmaf(fc2W[j * 64 + k], c1W[k * 64 + c], s);
            W2c[j * 64 + c] = s;
        } else if (j == 32) {
            float s = 0.f;
            for (int k = 0; k < 64; ++k) s = fmaf(b2[k], c1W[k * 64 + c], s);
            b2c[c] = s;
        }
    }
}

// single-block scan: rowptr[i+1]=sum(cnt[0..i]); + disq, pad rows of both H
__global__ __launch_bounds__(1024) void k_scan(const int* __restrict__ cnt,
                                               int* __restrict__ rowptr,
                                               float* __restrict__ disq,
                                               u16* __restrict__ HbA,
                                               u16* __restrict__ HbB) {
    __shared__ int wsum[16];
    __shared__ int carry;
    int t = threadIdx.x, wave = t >> 6, lane = t & 63;
    if (t == 0) { carry = 0; rowptr[0] = 0; }
    if (t < 64) HbA[(size_t)NN * 64 + t] = 0;
    else if (t < 128) HbB[(size_t)NN * 64 + (t - 64)] = 0;
    __syncthreads();
    for (int base = 0; base < NN; base += 1024) {
        int i = base + t;
        int x = (i < NN) ? cnt[i] : 0;
        if (i < NN) disq[i] = rsqrtf((float)x + 1.0f);  // +1 self-loop
        for (int off = 1; off < 64; off <<= 1) {
            int y = __shfl_up(x, off, 64);
            if (lane >= off) x += y;
        }
        if (lane == 63) wsum[wave] = x;
        __syncthreads();
        if (wave == 0 && lane < 16) {
            int w = wsum[lane];
            for (int off = 1; off < 16; off <<= 1) {
                int y = __shfl_up(w, off, 16);
                if (lane >= off) w += y;
            }
            wsum[lane] = w;
        }
        __syncthreads();
        int incl = carry + ((wave > 0) ? wsum[wave - 1] : 0) + x;
        if (i < NN) rowptr[i + 1] = incl;
        __syncthreads();
        if (t == 1023) carry = incl;
        __syncthreads();
    }
}

// ------- dual-role, LPT order: fc blocks FIRST, atomic-free fill backfills --
__global__ __launch_bounds__(256) void k_fill_fc(
    const int* __restrict__ src, const int* __restrict__ dst,
    const int* __restrict__ rowptr, const u16* __restrict__ rank,
    u16* __restrict__ esrc,
    const float* __restrict__ nf,
    const float* __restrict__ W1, const float* __restrict__ b1,
    const float* __restrict__ W2c, const float* __restrict__ b2c,
    const float* __restrict__ disq, u16* __restrict__ Hb) {
    if (blockIdx.x >= FC_BLOCKS) {  // fill role: no atomics, nt scatter
        int e = (blockIdx.x - FC_BLOCKS) * 256 + threadIdx.x;
        if (e < NE) {
            int d = dst[e];
            int pos = rowptr[d] + (int)__builtin_nontemporal_load(&rank[e]);
            __builtin_nontemporal_store((u16)src[e], &esrc[pos]);
        }
        return;
    }
    int lane = threadIdx.x & 63;
    int c = lane & 31, h = lane >> 5;
    int wid = (blockIdx.x * 256 + threadIdx.x) >> 6;
    int nwaves = (FC_BLOCKS * 256) >> 6;
    float w1[64], w2[32];
    #pragma unroll
    for (int j = 0; j < 64; ++j) w1[j] = W1[(h * 64 + j) * 32 + c];
    #pragma unroll
    for (int j = 0; j < 32; ++j) w2[j] = W2c[j * 64 + lane];
    float b1c = b1[c], b2l = b2c[lane];
    for (int n = wid; n < NN; n += nwaves) {
        float x0 = nf[(size_t)n * 128 + lane];
        float x1 = nf[(size_t)n * 128 + 64 + lane];
        float s0 = 0.f, s1 = 0.f;  // 2-way chain split
        #pragma unroll
        for (int j = 0; j < 32; ++j) {
            float xa = rlf(x0, j), xb = rlf(x1, j);
            float xc = rlf(x0, j + 32), xd = rlf(x1, j + 32);
            s0 = fmaf(h ? xb : xa, w1[j], s0);
            s1 = fmaf(h ? xd : xc, w1[j + 32], s1);
        }
        float s = s0 + s1;
        s += __shfl_xor(s, 32, 64);           // combine k-halves
        float hv = fmaxf(s + b1c, 0.f);       // lane l holds h1[l&31]
        float o0 = b2l, o1 = 0.f;
        #pragma unroll
        for (int j = 0; j < 16; ++j) {
            o0 = fmaf(rlf(hv, j), w2[j], o0);
            o1 = fmaf(rlf(hv, j + 16), w2[j + 16], o1);
        }
        Hb[(size_t)n * 64 + lane] = f2bf(disq[n] * (o0 + o1));
    }
}

// 4-row gather, direct broadcast index load: quarter q takes row (J+q);
// 16 lanes/quarter load the SAME esrc element (HW broadcast, L1-hot).
#define GRPA(J)                                                             \
    {                                                                       \
        int s = ((J) + q < d1) ? (int)esrc[base1 + (J) + q] : NN;           \
        uint2 v = *(const uint2*)(Hb + (((size_t)s) << 6) + c4);            \
        a0 += lo16(v.x); a1 += hi16(v.x); a2 += lo16(v.y); a3 += hi16(v.y); \
    }
#define GRPB(J)                                                             \
    {                                                                       \
        int s = ((J) + q < d2) ? (int)esrc[base2 + (J) + q] : NN;           \
        uint2 v = *(const uint2*)(Hb + (((size_t)s) << 6) + c4);            \
        g0 += lo16(v.x); g1 += hi16(v.x); g2 += lo16(v.y); g3 += hi16(v.y); \
    }

// ------ fused CSR conv + next-layer GEMV: 2 nodes/wave; W_next in LDS -------
__global__ __launch_bounds__(256) void k_csr_fused(
    const u16* __restrict__ Hb, const int* __restrict__ rowptr,
    const u16* __restrict__ esrc, const float* __restrict__ disq,
    const float* __restrict__ b, const float* __restrict__ res,
    float* __restrict__ out, const float* __restrict__ Wn,
    u16* __restrict__ HbN) {
    __shared__ float sW[64 * 64];
    for (int i = threadIdx.x; i < 4096; i += 256) sW[i] = Wn[i];
    __syncthreads();
    int lane = threadIdx.x & 63;
    int q = lane >> 4;
    int c4 = (lane & 15) * 4;
    int w = (blockIdx.x * 256 + threadIdx.x) >> 6;
    if (w >= NHALF) return;
    int n1 = w, n2 = w + NHALF;
    int base1 = rowptr[n1], d1 = rowptr[n1 + 1] - base1;
    int base2 = rowptr[n2], d2 = rowptr[n2 + 1] - base2;
    float a0 = 0.f, a1 = 0.f, a2 = 0.f, a3 = 0.f;
    float g0 = 0.f, g1 = 0.f, g2 = 0.f, g3 = 0.f;
    int dmin = min(d1, d2);
    int j = 0;
    for (; j + 16 <= dmin; j += 16) {
        GRPA(j) GRPB(j) GRPA(j + 4) GRPB(j + 4)
        GRPA(j + 8) GRPB(j + 8) GRPA(j + 12) GRPB(j + 12)
    }
    for (; j < dmin; j += 4) { GRPA(j) GRPB(j) }
    for (int ja = j; ja < d1; ja += 4) GRPA(ja)
    for (int jb = j; jb < d2; jb += 4) GRPB(jb)
    // combine quarters
    a0 += __shfl_xor(a0, 16, 64); a0 += __shfl_xor(a0, 32, 64);
    a1 += __shfl_xor(a1, 16, 64); a1 += __shfl_xor(a1, 32, 64);
    a2 += __shfl_xor(a2, 16, 64); a2 += __shfl_xor(a2, 32, 64);
    a3 += __shfl_xor(a3, 16, 64); a3 += __shfl_xor(a3, 32, 64);
    g0 += __shfl_xor(g0, 16, 64); g0 += __shfl_xor(g0, 32, 64);
    g1 += __shfl_xor(g1, 16, 64); g1 += __shfl_xor(g1, 32, 64);
    g2 += __shfl_xor(g2, 16, 64); g2 += __shfl_xor(g2, 32, 64);
    g3 += __shfl_xor(g3, 16, 64); g3 += __shfl_xor(g3, 32, 64);
    // v for node n (q0: n1 ch c4.. ; q1: n2 ch c4..) in registers vv[0..3]
    float vv[4] = {0.f, 0.f, 0.f, 0.f};
    if (q < 2) {
        int n = (q == 0) ? n1 : n2;
        float e0 = (q == 0) ? a0 : g0;
        float e1 = (q == 0) ? a1 : g1;
        float e2 = (q == 0) ? a2 : g2;
        float e3 = (q == 0) ? a3 : g3;
        uint2 sv = *(const uint2*)(Hb + (((size_t)n) << 6) + c4);  // self-loop
        e0 += lo16(sv.x); e1 += hi16(sv.x); e2 += lo16(sv.y); e3 += hi16(sv.y);
        float dn = disq[n];
        float4 bv = *(const float4*)(b + c4);
        float v0 = dn * e0 + bv.x;
        float v1 = dn * e1 + bv.y;
        float v2 = dn * e2 + bv.z;
        float v3 = dn * e3 + bv.w;
        v0 = (v0 >= 0.f) ? v0 : 0.2f * v0;  // lrelu (all fused layers use it)
        v1 = (v1 >= 0.f) ? v1 : 0.2f * v1;
        v2 = (v2 >= 0.f) ? v2 : 0.2f * v2;
        v3 = (v3 >= 0.f) ? v3 : 0.2f * v3;
        if (res) {
            float4 r = *(const float4*)(res + (((size_t)n) << 6) + c4);
            v0 += r.x; v1 += r.y; v2 += r.z; v3 += r.w;
        }
        vv[0] = v0; vv[1] = v1; vv[2] = v2; vv[3] = v3;
        if (out) {
            float4 o;
            o.x = v0; o.y = v1; o.z = v2; o.w = v3;
            *(float4*)(out + (((size_t)n) << 6) + c4) = o;
        }
    }
    // fused GEMV: half-wave 0 -> n1, half-wave 1 -> n2; lane covers 2 channels
    int cp = (lane & 31) * 2;
    float o0 = 0.f, o1 = 0.f, o2 = 0.f, o3 = 0.f;  // 2-way k-split per channel
    #pragma unroll
    for (int k = 0; k < 32; ++k) {
        float vA0 = rlf(vv[k & 3], k >> 2);            // n1 v[k]
        float vB0 = rlf(vv[k & 3], 16 + (k >> 2));     // n2 v[k]
        float vA1 = rlf(vv[k & 3], (k + 32) >> 2);     // n1 v[k+32]
        float vB1 = rlf(vv[k & 3], 16 + ((k + 32) >> 2));  // n2 v[k+32]
        float vk0 = (lane < 32) ? vA0 : vB0;
        float vk1 = (lane < 32) ? vA1 : vB1;
        float2 w0 = *(const float2*)(sW + k * 64 + cp);
        float2 w1 = *(const float2*)(sW + (k + 32) * 64 + cp);
        o0 = fmaf(vk0, w0.x, o0);
        o1 = fmaf(vk0, w0.y, o1);
        o2 = fmaf(vk1, w1.x, o2);
        o3 = fmaf(vk1, w1.y, o3);
    }
    int nn = (lane < 32) ? n1 : n2;
    float dnn = disq[nn];
    u32 packed = (u32)f2bf(dnn * (o0 + o2)) | ((u32)f2bf(dnn * (o1 + o3)) << 16);
    *(u32*)(HbN + (((size_t)nn) << 6) + cp) = packed;
}

// ---------------- conv4 + residual + final 64->2 projection (2 nodes/wave) --
__global__ __launch_bounds__(256) void k_csr_conv_final(
    const u16* __restrict__ Hb, const int* __restrict__ rowptr,
    const u16* __restrict__ esrc, const float* __restrict__ disq,
    const float* __restrict__ b, const float* __restrict__ res,
    const float* __restrict__ FW, const float* __restrict__ fb,
    float* __restrict__ out) {
    int lane = threadIdx.x & 63;
    int q = lane >> 4;
    int c4 = (lane & 15) * 4;
    int w = (blockIdx.x * 256 + threadIdx.x) >> 6;
    if (w >= NHALF) return;
    int n1 = w, n2 = w + NHALF;
    int base1 = rowptr[n1], d1 = rowptr[n1 + 1] - base1;
    int base2 = rowptr[n2], d2 = rowptr[n2 + 1] - base2;
    float a0 = 0.f, a1 = 0.f, a2 = 0.f, a3 = 0.f;
    float g0 = 0.f, g1 = 0.f, g2 = 0.f, g3 = 0.f;
    int dmin = min(d1, d2);
    int j = 0;
    for (; j + 16 <= dmin; j += 16) {
        GRPA(j) GRPB(j) GRPA(j + 4) GRPB(j + 4)
        GRPA(j + 8) GRPB(j + 8) GRPA(j + 12) GRPB(j + 12)
    }
    for (; j < dmin; j += 4) { GRPA(j) GRPB(j) }
    for (int ja = j; ja < d1; ja += 4) GRPA(ja)
    for (int jb = j; jb < d2; jb += 4) GRPB(jb)
    a0 += __shfl_xor(a0, 16, 64); a0 += __shfl_xor(a0, 32, 64);
    a1 += __shfl_xor(a1, 16, 64); a1 += __shfl_xor(a1, 32, 64);
    a2 += __shfl_xor(a2, 16, 64); a2 += __shfl_xor(a2, 32, 64);
    a3 += __shfl_xor(a3, 16, 64); a3 += __shfl_xor(a3, 32, 64);
    g0 += __shfl_xor(g0, 16, 64); g0 += __shfl_xor(g0, 32, 64);
    g1 += __shfl_xor(g1, 16, 64); g1 += __shfl_xor(g1, 32, 64);
    g2 += __shfl_xor(g2, 16, 64); g2 += __shfl_xor(g2, 32, 64);
    g3 += __shfl_xor(g3, 16, 64); g3 += __shfl_xor(g3, 32, 64);
    float p0 = 0.f, p1 = 0.f;
    int n = (q == 0) ? n1 : n2;
    if (q < 2) {
        float e0 = (q == 0) ? a0 : g0;
        float e1 = (q == 0) ? a1 : g1;
        float e2 = (q == 0) ? a2 : g2;
        float e3 = (q == 0) ? a3 : g3;
        uint2 sv = *(const uint2*)(Hb + (((size_t)n) << 6) + c4);
        e0 += lo16(sv.x); e1 += hi16(sv.x); e2 += lo16(sv.y); e3 += hi16(sv.y);
        float dn = disq[n];
        float4 bv = *(const float4*)(b + c4);
        float4 r = *(const float4*)(res + (((size_t)n) << 6) + c4);
        float v0 = dn * e0 + bv.x + r.x;   // out4, no lrelu
        float v1 = dn * e1 + bv.y + r.y;
        float v2 = dn * e2 + bv.z + r.z;
        float v3 = dn * e3 + bv.w + r.w;
        float4 f01 = *(const float4*)(FW + c4 * 2);
        float4 f23 = *(const float4*)(FW + c4 * 2 + 4);
        p0 = v0 * f01.x + v1 * f01.z + v2 * f23.x + v3 * f23.z;
        p1 = v0 * f01.y + v1 * f01.w + v2 * f23.y + v3 * f23.w;
    }
    for (int off = 1; off < 16; off <<= 1) {  // reduce within 16-lane quarter
        p0 += __shfl_xor(p0, off, 64);
        p1 += __shfl_xor(p1, off, 64);
    }
    if (lane == 0 || lane == 16) {
        out[n * 2 + 0] = p0 + fb[0];
        out[n * 2 + 1] = p1 + fb[1];
    }
}

extern "C" void kernel_launch(void* const* d_in, const int* in_sizes, int n_in,
                              void* d_out, int out_size, void* d_ws, size_t ws_size,
                              hipStream_t stream) {
    const float* nf   = (const float*)d_in[0];
    const int*   ei   = (const int*)d_in[1];
    const float* fc1W = (const float*)d_in[2];
    const float* fc1b = (const float*)d_in[3];
    const float* fc2W = (const float*)d_in[4];
    const float* fc2b = (const float*)d_in[5];
    const float* cW[4] = {(const float*)d_in[6], (const float*)d_in[8],
                          (const float*)d_in[10], (const float*)d_in[12]};
    const float* cb[4] = {(const float*)d_in[7], (const float*)d_in[9],
                          (const float*)d_in[11], (const float*)d_in[13]};
    const float* fW = (const float*)d_in[14];
    const float* fb = (const float*)d_in[15];
    const int* src = ei;
    const int* dst = ei + NE;

    float* ws     = (float*)d_ws;
    float* disq   = ws;                          // 50048 f
    int*   cnt    = (int*)(ws + 50048);          // 50048 i (histogram)
    int*   rowptr = cnt + 50048;                 // 50056 i
    u16*   esrc   = (u16*)(rowptr + 50056);      // 800000 u16
    u16*   rank   = esrc + 800000;               // 800000 u16
    float* W2c    = (float*)(rank + 800000);     // 2048 f
    float* b2c    = W2c + 2048;                  // 64 f
    float* B0     = b2c + 64;                    // NN*64 f
    float* B1     = B0 + (size_t)NN * 64;        // NN*64 f
    u16*   HbA    = (u16*)(B1 + (size_t)NN * 64);// HBSZ u16
    u16*   HbB    = HbA + HBSZ;                  // HBSZ u16

    // ---- CSR build + weight fold + fc (LPT overlap: fc first) ----
    hipMemsetAsync(cnt, 0, 50048 * sizeof(int), stream);
    k_hist_foldw<<<HIST_BLOCKS + 9, 256, 0, stream>>>(dst, cnt, rank, fc2W, fc2b,
                                                      cW[0], W2c, b2c);
    k_scan<<<1, 1024, 0, stream>>>(cnt, rowptr, disq, HbA, HbB);
    k_fill_fc<<<FC_BLOCKS + FILL_BLOCKS, 256, 0, stream>>>(
        src, dst, rowptr, rank, esrc, nf, fc1W, fc1b, W2c, b2c, disq, HbA);

    const int cgrid = (NHALF * 64 + 255) / 256;  // one wave per 2 nodes

    // conv1: out1 -> B1; epilogue GEMV W2 -> HbB
    k_csr_fused<<<cgrid, 256, 0, stream>>>(HbA, rowptr, esrc, disq, cb[0],
                                           nullptr, B1, cW[1], HbB);
    // conv2: out2 = lrelu(conv)+out1 -> B0; GEMV W3 -> HbA
    k_csr_fused<<<cgrid, 256, 0, stream>>>(HbB, rowptr, esrc, disq, cb[1],
                                           B1, B0, cW[2], HbA);
    // conv3: out3 (not stored); GEMV W4 -> HbB
    k_csr_fused<<<cgrid, 256, 0, stream>>>(HbA, rowptr, esrc, disq, cb[2],
                                           nullptr, nullptr, cW[3], HbB);
    // conv4 + residual(out2=B0) + final projection -> d_out
    k_csr_conv_final<<<cgrid, 256, 0, stream>>>(HbB, rowptr, esrc, disq, cb[3],
                                                B0, fW, fb, (float*)d_out);
}

// Round 20
// 289.835 us; speedup vs baseline: 1.1096x; 1.1096x over previous
//
#include <hip/hip_runtime.h>

#define NN 50000
#define NHALF 25000
#define NE 800000
#define HIST_BLOCKS ((NE + 255) / 256)   // 3125
#define FILL_BLOCKS HIST_BLOCKS          // 3125
#define FC_BLOCKS 1024
#define HBSZ ((size_t)(NN + 1) * 64)     // u16 elems per H table (row NN = zeros)

typedef unsigned short u16;
typedef unsigned int u32;

__device__ inline float rlf(float v, int l) {
    return __int_as_float(__builtin_amdgcn_readlane(__float_as_int(v), l));
}
__device__ inline u16 f2bf(float f) {  // round-to-nearest-even
    u32 u = __float_as_uint(f);
    u32 r = (u + 0x7FFFu + ((u >> 16) & 1u)) >> 16;
    return (u16)r;
}
__device__ inline float lo16(u32 q) { return __uint_as_float(q << 16); }
__device__ inline float hi16(u32 q) { return __uint_as_float(q & 0xffff0000u); }

// ------- hist (edges, also records per-edge rank) + weight-fold dual-role ---
__global__ __launch_bounds__(256) void k_hist_foldw(
    const int* __restrict__ dst, int* __restrict__ cnt, u16* __restrict__ rank,
    const float* __restrict__ fc2W, const float* __restrict__ b2,
    const float* __restrict__ c1W, float* __restrict__ W2c,
    float* __restrict__ b2c) {
    if (blockIdx.x < HIST_BLOCKS) {
        int e = blockIdx.x * 256 + threadIdx.x;
        if (e < NE) {
            u16 r = (u16)atomicAdd(&cnt[dst[e]], 1);
            __builtin_nontemporal_store(r, &rank[e]);
        }
    } else {
        int j = (blockIdx.x - HIST_BLOCKS) * 4 + (threadIdx.x >> 6);
        int c = threadIdx.x & 63;
        if (j < 32) {
            float s = 0.f;
            for (int k = 0; k < 64; ++k) s = fmaf(fc2W[j * 64 + k], c1W[k * 64 + c], s);
            W2c[j * 64 + c] = s;
        } else if (j == 32) {
            float s = 0.f;
            for (int k = 0; k < 64; ++k) s = fmaf(b2[k], c1W[k * 64 + c], s);
            b2c[c] = s;
        }
    }
}

// single-block scan: rowptr[i+1]=sum(cnt[0..i]); + disq, pad rows of both H
__global__ __launch_bounds__(1024) void k_scan(const int* __restrict__ cnt,
                                               int* __restrict__ rowptr,
                                               float* __restrict__ disq,
                                               u16* __restrict__ HbA,
                                               u16* __restrict__ HbB) {
    __shared__ int wsum[16];
    __shared__ int carry;
    int t = threadIdx.x, wave = t >> 6, lane = t & 63;
    if (t == 0) { carry = 0; rowptr[0] = 0; }
    if (t < 64) HbA[(size_t)NN * 64 + t] = 0;
    else if (t < 128) HbB[(size_t)NN * 64 + (t - 64)] = 0;
    __syncthreads();
    for (int base = 0; base < NN; base += 1024) {
        int i = base + t;
        int x = (i < NN) ? cnt[i] : 0;
        if (i < NN) disq[i] = rsqrtf((float)x + 1.0f);  // +1 self-loop
        for (int off = 1; off < 64; off <<= 1) {
            int y = __shfl_up(x, off, 64);
            if (lane >= off) x += y;
        }
        if (lane == 63) wsum[wave] = x;
        __syncthreads();
        if (wave == 0 && lane < 16) {
            int w = wsum[lane];
            for (int off = 1; off < 16; off <<= 1) {
                int y = __shfl_up(w, off, 16);
                if (lane >= off) w += y;
            }
            wsum[lane] = w;
        }
        __syncthreads();
        int incl = carry + ((wave > 0) ? wsum[wave - 1] : 0) + x;
        if (i < NN) rowptr[i + 1] = incl;
        __syncthreads();
        if (t == 1023) carry = incl;
        __syncthreads();
    }
}

// ------- dual-role, LPT order: fc blocks FIRST, atomic-free fill backfills --
__global__ __launch_bounds__(256) void k_fill_fc(
    const int* __restrict__ src, const int* __restrict__ dst,
    const int* __restrict__ rowptr, const u16* __restrict__ rank,
    u16* __restrict__ esrc,
    const float* __restrict__ nf,
    const float* __restrict__ W1, const float* __restrict__ b1,
    const float* __restrict__ W2c, const float* __restrict__ b2c,
    const float* __restrict__ disq, u16* __restrict__ Hb) {
    if (blockIdx.x >= FC_BLOCKS) {  // fill role: no atomics, nt scatter
        int e = (blockIdx.x - FC_BLOCKS) * 256 + threadIdx.x;
        if (e < NE) {
            int d = dst[e];
            int pos = rowptr[d] + (int)__builtin_nontemporal_load(&rank[e]);
            __builtin_nontemporal_store((u16)src[e], &esrc[pos]);
        }
        return;
    }
    int lane = threadIdx.x & 63;
    int c = lane & 31, h = lane >> 5;
    int wid = (blockIdx.x * 256 + threadIdx.x) >> 6;
    int nwaves = (FC_BLOCKS * 256) >> 6;
    float w1[64], w2[32];
    #pragma unroll
    for (int j = 0; j < 64; ++j) w1[j] = W1[(h * 64 + j) * 32 + c];
    #pragma unroll
    for (int j = 0; j < 32; ++j) w2[j] = W2c[j * 64 + lane];
    float b1c = b1[c], b2l = b2c[lane];
    for (int n = wid; n < NN; n += nwaves) {
        float x0 = nf[(size_t)n * 128 + lane];
        float x1 = nf[(size_t)n * 128 + 64 + lane];
        float s0 = 0.f, s1 = 0.f;  // 2-way chain split
        #pragma unroll
        for (int j = 0; j < 32; ++j) {
            float xa = rlf(x0, j), xb = rlf(x1, j);
            float xc = rlf(x0, j + 32), xd = rlf(x1, j + 32);
            s0 = fmaf(h ? xb : xa, w1[j], s0);
            s1 = fmaf(h ? xd : xc, w1[j + 32], s1);
        }
        float s = s0 + s1;
        s += __shfl_xor(s, 32, 64);           // combine k-halves
        float hv = fmaxf(s + b1c, 0.f);       // lane l holds h1[l&31]
        float o0 = b2l, o1 = 0.f;
        #pragma unroll
        for (int j = 0; j < 16; ++j) {
            o0 = fmaf(rlf(hv, j), w2[j], o0);
            o1 = fmaf(rlf(hv, j + 16), w2[j + 16], o1);
        }
        Hb[(size_t)n * 64 + lane] = f2bf(disq[n] * (o0 + o1));
    }
}

// 4-row gather for chain A/B: quarter-wave q takes row (J+q); lane = 4 channels
// row-index distribution via ds_bpermute (1 LDS op, off the VALU path)
#define GRPA(J)                                                             \
    {                                                                       \
        int s = __builtin_amdgcn_ds_bpermute(qb + ((J) << 2), idx1);        \
        uint2 v = *(const uint2*)(Hb + (((size_t)s) << 6) + c4);            \
        a0 += lo16(v.x); a1 += hi16(v.x); a2 += lo16(v.y); a3 += hi16(v.y); \
    }
#define GRPB(J)                                                             \
    {                                                                       \
        int s = __builtin_amdgcn_ds_bpermute(qb + ((J) << 2), idx2);        \
        uint2 v = *(const uint2*)(Hb + (((size_t)s) << 6) + c4);            \
        g0 += lo16(v.x); g1 += hi16(v.x); g2 += lo16(v.y); g3 += hi16(v.y); \
    }

// ------ fused CSR conv + next-layer GEMV: 2 nodes/wave; W_next in LDS -------
// v = act(disq*(gather)+b)[+res]; optional out write; HbN = bf16(disq*(v@Wn))
__global__ __launch_bounds__(256) void k_csr_fused(
    const u16* __restrict__ Hb, const int* __restrict__ rowptr,
    const u16* __restrict__ esrc, const float* __restrict__ disq,
    const float* __restrict__ b, const float* __restrict__ res,
    float* __restrict__ out, const float* __restrict__ Wn,
    u16* __restrict__ HbN) {
    __shared__ float sW[64 * 64];
    for (int i = threadIdx.x; i < 4096; i += 256) sW[i] = Wn[i];
    __syncthreads();
    int lane = threadIdx.x & 63;
    int q = lane >> 4;
    int qb = q << 2;
    int c4 = (lane & 15) * 4;
    int w = (blockIdx.x * 256 + threadIdx.x) >> 6;
    if (w >= NHALF) return;
    int n1 = w, n2 = w + NHALF;
    int base1 = rowptr[n1], end1 = rowptr[n1 + 1];
    int base2 = rowptr[n2], end2 = rowptr[n2 + 1];
    float a0 = 0.f, a1 = 0.f, a2 = 0.f, a3 = 0.f;
    float g0 = 0.f, g1 = 0.f, g2 = 0.f, g3 = 0.f;
    while (base1 < end1 || base2 < end2) {
        int m1 = min(max(end1 - base1, 0), 64);
        int m2 = min(max(end2 - base2, 0), 64);
        int idx1 = (lane < m1) ? (int)esrc[base1 + lane] : NN;  // NN = zero row
        int idx2 = (lane < m2) ? (int)esrc[base2 + lane] : NN;
        int m = max(m1, m2);
        int j = 0;
        for (; j + 16 <= m; j += 16) {
            GRPA(j) GRPB(j) GRPA(j + 4) GRPB(j + 4)
            GRPA(j + 8) GRPB(j + 8) GRPA(j + 12) GRPB(j + 12)
        }
        for (; j < m; j += 4) { GRPA(j) GRPB(j) }
        base1 += 64;
        base2 += 64;
    }
    // combine quarters
    a0 += __shfl_xor(a0, 16, 64); a0 += __shfl_xor(a0, 32, 64);
    a1 += __shfl_xor(a1, 16, 64); a1 += __shfl_xor(a1, 32, 64);
    a2 += __shfl_xor(a2, 16, 64); a2 += __shfl_xor(a2, 32, 64);
    a3 += __shfl_xor(a3, 16, 64); a3 += __shfl_xor(a3, 32, 64);
    g0 += __shfl_xor(g0, 16, 64); g0 += __shfl_xor(g0, 32, 64);
    g1 += __shfl_xor(g1, 16, 64); g1 += __shfl_xor(g1, 32, 64);
    g2 += __shfl_xor(g2, 16, 64); g2 += __shfl_xor(g2, 32, 64);
    g3 += __shfl_xor(g3, 16, 64); g3 += __shfl_xor(g3, 32, 64);
    // v for node n (q0: n1 ch c4.. ; q1: n2 ch c4..) in registers vv[0..3]
    float vv[4] = {0.f, 0.f, 0.f, 0.f};
    if (q < 2) {
        int n = (q == 0) ? n1 : n2;
        float e0 = (q == 0) ? a0 : g0;
        float e1 = (q == 0) ? a1 : g1;
        float e2 = (q == 0) ? a2 : g2;
        float e3 = (q == 0) ? a3 : g3;
        uint2 sv = *(const uint2*)(Hb + (((size_t)n) << 6) + c4);  // self-loop
        e0 += lo16(sv.x); e1 += hi16(sv.x); e2 += lo16(sv.y); e3 += hi16(sv.y);
        float dn = disq[n];
        float4 bv = *(const float4*)(b + c4);
        float v0 = dn * e0 + bv.x;
        float v1 = dn * e1 + bv.y;
        float v2 = dn * e2 + bv.z;
        float v3 = dn * e3 + bv.w;
        v0 = (v0 >= 0.f) ? v0 : 0.2f * v0;  // lrelu (all fused layers use it)
        v1 = (v1 >= 0.f) ? v1 : 0.2f * v1;
        v2 = (v2 >= 0.f) ? v2 : 0.2f * v2;
        v3 = (v3 >= 0.f) ? v3 : 0.2f * v3;
        if (res) {
            float4 r = *(const float4*)(res + (((size_t)n) << 6) + c4);
            v0 += r.x; v1 += r.y; v2 += r.z; v3 += r.w;
        }
        vv[0] = v0; vv[1] = v1; vv[2] = v2; vv[3] = v3;
        if (out) {
            float4 o;
            o.x = v0; o.y = v1; o.z = v2; o.w = v3;
            *(float4*)(out + (((size_t)n) << 6) + c4) = o;
        }
    }
    // fused GEMV: half-wave 0 -> n1, half-wave 1 -> n2; lane covers 2 channels
    int cp = (lane & 31) * 2;
    float o0 = 0.f, o1 = 0.f, o2 = 0.f, o3 = 0.f;  // 2-way k-split per channel
    #pragma unroll
    for (int k = 0; k < 32; ++k) {
        float vA0 = rlf(vv[k & 3], k >> 2);            // n1 v[k]
        float vB0 = rlf(vv[k & 3], 16 + (k >> 2));     // n2 v[k]
        float vA1 = rlf(vv[k & 3], (k + 32) >> 2);     // n1 v[k+32]
        float vB1 = rlf(vv[k & 3], 16 + ((k + 32) >> 2));  // n2 v[k+32]
        float vk0 = (lane < 32) ? vA0 : vB0;
        float vk1 = (lane < 32) ? vA1 : vB1;
        float2 w0 = *(const float2*)(sW + k * 64 + cp);
        float2 w1 = *(const float2*)(sW + (k + 32) * 64 + cp);
        o0 = fmaf(vk0, w0.x, o0);
        o1 = fmaf(vk0, w0.y, o1);
        o2 = fmaf(vk1, w1.x, o2);
        o3 = fmaf(vk1, w1.y, o3);
    }
    int nn = (lane < 32) ? n1 : n2;
    float dnn = disq[nn];
    u32 packed = (u32)f2bf(dnn * (o0 + o2)) | ((u32)f2bf(dnn * (o1 + o3)) << 16);
    *(u32*)(HbN + (((size_t)nn) << 6) + cp) = packed;
}

// ---------------- conv4 + residual + final 64->2 projection (2 nodes/wave) --
__global__ __launch_bounds__(256) void k_csr_conv_final(
    const u16* __restrict__ Hb, const int* __restrict__ rowptr,
    const u16* __restrict__ esrc, const float* __restrict__ disq,
    const float* __restrict__ b, const float* __restrict__ res,
    const float* __restrict__ FW, const float* __restrict__ fb,
    float* __restrict__ out) {
    int lane = threadIdx.x & 63;
    int q = lane >> 4;
    int qb = q << 2;
    int c4 = (lane & 15) * 4;
    int w = (blockIdx.x * 256 + threadIdx.x) >> 6;
    if (w >= NHALF) return;
    int n1 = w, n2 = w + NHALF;
    int base1 = rowptr[n1], end1 = rowptr[n1 + 1];
    int base2 = rowptr[n2], end2 = rowptr[n2 + 1];
    float a0 = 0.f, a1 = 0.f, a2 = 0.f, a3 = 0.f;
    float g0 = 0.f, g1 = 0.f, g2 = 0.f, g3 = 0.f;
    while (base1 < end1 || base2 < end2) {
        int m1 = min(max(end1 - base1, 0), 64);
        int m2 = min(max(end2 - base2, 0), 64);
        int idx1 = (lane < m1) ? (int)esrc[base1 + lane] : NN;
        int idx2 = (lane < m2) ? (int)esrc[base2 + lane] : NN;
        int m = max(m1, m2);
        int j = 0;
        for (; j + 16 <= m; j += 16) {
            GRPA(j) GRPB(j) GRPA(j + 4) GRPB(j + 4)
            GRPA(j + 8) GRPB(j + 8) GRPA(j + 12) GRPB(j + 12)
        }
        for (; j < m; j += 4) { GRPA(j) GRPB(j) }
        base1 += 64;
        base2 += 64;
    }
    a0 += __shfl_xor(a0, 16, 64); a0 += __shfl_xor(a0, 32, 64);
    a1 += __shfl_xor(a1, 16, 64); a1 += __shfl_xor(a1, 32, 64);
    a2 += __shfl_xor(a2, 16, 64); a2 += __shfl_xor(a2, 32, 64);
    a3 += __shfl_xor(a3, 16, 64); a3 += __shfl_xor(a3, 32, 64);
    g0 += __shfl_xor(g0, 16, 64); g0 += __shfl_xor(g0, 32, 64);
    g1 += __shfl_xor(g1, 16, 64); g1 += __shfl_xor(g1, 32, 64);
    g2 += __shfl_xor(g2, 16, 64); g2 += __shfl_xor(g2, 32, 64);
    g3 += __shfl_xor(g3, 16, 64); g3 += __shfl_xor(g3, 32, 64);
    float p0 = 0.f, p1 = 0.f;
    int n = (q == 0) ? n1 : n2;
    if (q < 2) {
        float e0 = (q == 0) ? a0 : g0;
        float e1 = (q == 0) ? a1 : g1;
        float e2 = (q == 0) ? a2 : g2;
        float e3 = (q == 0) ? a3 : g3;
        uint2 sv = *(const uint2*)(Hb + (((size_t)n) << 6) + c4);
        e0 += lo16(sv.x); e1 += hi16(sv.x); e2 += lo16(sv.y); e3 += hi16(sv.y);
        float dn = disq[n];
        float4 bv = *(const float4*)(b + c4);
        float4 r = *(const float4*)(res + (((size_t)n) << 6) + c4);
        float v0 = dn * e0 + bv.x + r.x;   // out4, no lrelu
        float v1 = dn * e1 + bv.y + r.y;
        float v2 = dn * e2 + bv.z + r.z;
        float v3 = dn * e3 + bv.w + r.w;
        float4 f01 = *(const float4*)(FW + c4 * 2);
        float4 f23 = *(const float4*)(FW + c4 * 2 + 4);
        p0 = v0 * f01.x + v1 * f01.z + v2 * f23.x + v3 * f23.z;
        p1 = v0 * f01.y + v1 * f01.w + v2 * f23.y + v3 * f23.w;
    }
    for (int off = 1; off < 16; off <<= 1) {  // reduce within 16-lane quarter
        p0 += __shfl_xor(p0, off, 64);
        p1 += __shfl_xor(p1, off, 64);
    }
    if (lane == 0 || lane == 16) {
        out[n * 2 + 0] = p0 + fb[0];
        out[n * 2 + 1] = p1 + fb[1];
    }
}

extern "C" void kernel_launch(void* const* d_in, const int* in_sizes, int n_in,
                              void* d_out, int out_size, void* d_ws, size_t ws_size,
                              hipStream_t stream) {
    const float* nf   = (const float*)d_in[0];
    const int*   ei   = (const int*)d_in[1];
    const float* fc1W = (const float*)d_in[2];
    const float* fc1b = (const float*)d_in[3];
    const float* fc2W = (const float*)d_in[4];
    const float* fc2b = (const float*)d_in[5];
    const float* cW[4] = {(const float*)d_in[6], (const float*)d_in[8],
                          (const float*)d_in[10], (const float*)d_in[12]};
    const float* cb[4] = {(const float*)d_in[7], (const float*)d_in[9],
                          (const float*)d_in[11], (const float*)d_in[13]};
    const float* fW = (const float*)d_in[14];
    const float* fb = (const float*)d_in[15];
    const int* src = ei;
    const int* dst = ei + NE;

    float* ws     = (float*)d_ws;
    float* disq   = ws;                          // 50048 f
    int*   cnt    = (int*)(ws + 50048);          // 50048 i (histogram)
    int*   rowptr = cnt + 50048;                 // 50056 i
    u16*   esrc   = (u16*)(rowptr + 50056);      // 800000 u16
    u16*   rank   = esrc + 800000;               // 800000 u16
    float* W2c    = (float*)(rank + 800000);     // 2048 f
    float* b2c    = W2c + 2048;                  // 64 f
    float* B0     = b2c + 64;                    // NN*64 f
    float* B1     = B0 + (size_t)NN * 64;        // NN*64 f
    u16*   HbA    = (u16*)(B1 + (size_t)NN * 64);// HBSZ u16
    u16*   HbB    = HbA + HBSZ;                  // HBSZ u16

    // ---- CSR build + weight fold + fc (LPT overlap: fc first) ----
    hipMemsetAsync(cnt, 0, 50048 * sizeof(int), stream);
    k_hist_foldw<<<HIST_BLOCKS + 9, 256, 0, stream>>>(dst, cnt, rank, fc2W, fc2b,
                                                      cW[0], W2c, b2c);
    k_scan<<<1, 1024, 0, stream>>>(cnt, rowptr, disq, HbA, HbB);
    k_fill_fc<<<FC_BLOCKS + FILL_BLOCKS, 256, 0, stream>>>(
        src, dst, rowptr, rank, esrc, nf, fc1W, fc1b, W2c, b2c, disq, HbA);

    const int cgrid = (NHALF * 64 + 255) / 256;  // one wave per 2 nodes

    // conv1: out1 -> B1; epilogue GEMV W2 -> HbB
    k_csr_fused<<<cgrid, 256, 0, stream>>>(HbA, rowptr, esrc, disq, cb[0],
                                           nullptr, B1, cW[1], HbB);
    // conv2: out2 = lrelu(conv)+out1 -> B0; GEMV W3 -> HbA
    k_csr_fused<<<cgrid, 256, 0, stream>>>(HbB, rowptr, esrc, disq, cb[1],
                                           B1, B0, cW[2], HbA);
    // conv3: out3 (not stored); GEMV W4 -> HbB
    k_csr_fused<<<cgrid, 256, 0, stream>>>(HbA, rowptr, esrc, disq, cb[2],
                                           nullptr, nullptr, cW[3], HbB);
    // conv4 + residual(out2=B0) + final projection -> d_out
    k_csr_conv_final<<<cgrid, 256, 0, stream>>>(HbB, rowptr, esrc, disq, cb[3],
                                                B0, fW, fb, (float*)d_out);
}